// Round 19
// baseline (324.309 us; speedup 1.0000x reference)
//
#include <hip/hip_runtime.h>
#include <hip/hip_fp16.h>
#include <stdint.h>

#define TOKENS 4096
#define HDIM   2048
#define IDIM   5632
#define BM 128
#define BN 128
#define BK 64

#define G1_NP  11264
#define G1_KSB (G1_NP * 64)    // halves per K-tile panel of Bt (gate/up)
#define G2_KSB (HDIM * 64)     // halves per K-tile panel of Btd (down)

typedef _Float16 f16x8 __attribute__((ext_vector_type(8)));
typedef float    f32x4 __attribute__((ext_vector_type(4)));

// ---------- fp4 decode helpers (verified rounds 1-18) ----------
__device__ __forceinline__ uint32_t dec2(uint32_t z, uint32_t s2u) {
    uint32_t sgn = (z << 12) & 0x80008000u;
    uint32_t h   = ((z << 9) & 0x0E000E00u) | sgn;
    __half2 hv = __builtin_bit_cast(__half2, h);
    __half2 sv = __builtin_bit_cast(__half2, s2u);
    __half2 r  = __hmul2(hv, sv);
    return __builtin_bit_cast(uint32_t, r);
}
__device__ __forceinline__ int4 dec8(uint32_t w, uint32_t s2u) {
    int4 d;
    d.x = (int)dec2( w        & 0x000F000Fu, s2u);
    d.y = (int)dec2((w >> 4)  & 0x000F000Fu, s2u);
    d.z = (int)dec2((w >> 8)  & 0x000F000Fu, s2u);
    d.w = (int)dec2((w >> 12) & 0x000F000Fu, s2u);
    return d;
}
__device__ __forceinline__ uint32_t scale_s2u(float sc) {
    uint16_t hs = __builtin_bit_cast(uint16_t, __float2half(sc * 16384.0f));
    return (uint32_t)hs * 0x00010001u;
}
__device__ __forceinline__ uint32_t packh(float lo, float hi) {
    __half2 h2 = __halves2half2(__float2half(lo), __float2half(hi));
    return __builtin_bit_cast(uint32_t, h2);
}
__device__ __forceinline__ void gl_lds16(const void* g, void* l) {
    __builtin_amdgcn_global_load_lds(
        (const __attribute__((address_space(1))) uint32_t*)g,
        (__attribute__((address_space(3))) uint32_t*)l, 16, 0, 0);
}

// ---------- hidden fp32 -> f16, sigma k-order within each 8-group ----------
__global__ __launch_bounds__(256) void convert_hidden(
    const float* __restrict__ src, __half* __restrict__ dst)
{
    int idx = blockIdx.x * 256 + threadIdx.x;   // one 8-group per thread
    const float4* s = (const float4*)src + (size_t)idx * 2;
    float4 a = s[0], b = s[1];                  // a = x0..x3, b = x4..x7
    int4 v;
    v.x = (int)packh(a.x, b.x);                 // pos 0,1 = x0,x4
    v.y = (int)packh(a.y, b.y);
    v.z = (int)packh(a.z, b.z);
    v.w = (int)packh(a.w, b.w);
    *((int4*)dst + idx) = v;
}

// ---------- dequant W_gu v5 (r16/r17 control): 32-col gate/up interleave ->
// Bt[32][11264][64], linear k-word slots; LDS-staged, both sides coalesced. ----------
__global__ __launch_bounds__(256) void dequant_wgu5(
    const uint32_t* __restrict__ W, const float* __restrict__ S,
    __half* __restrict__ Bt)
{
    __shared__ __half L[256 * 64];   // 32 KB
    const int kt = blockIdx.y;                       // 0..31
    const int t  = threadIdx.x;
    const int np = blockIdx.x * 256 + t;             // interleaved row
    const int sc = (np >> 6) * 32 + (np & 31) + (((np >> 5) & 1) ? IDIM : 0);
    uint32_t s2u = scale_s2u(S[(size_t)(kt >> 1) * (2 * IDIM) + sc]);
    #pragma unroll
    for (int j = 0; j < 8; ++j) {
        uint32_t w = W[(size_t)(kt * 8 + j) * (2 * IDIM) + sc];
        int4 d = dec8(w, s2u);
        *(int4*)&L[t * 64 + ((j ^ (t & 7)) << 3)] = d;   // bank-spread slot
    }
    __syncthreads();
    __half* dst = Bt + (size_t)kt * G1_KSB + (size_t)blockIdx.x * 256 * 64;
    #pragma unroll
    for (int k = 0; k < 8; ++k) {
        int c = k * 256 + t;                 // chunk: row=c>>3, word s=c&7
        int row = c >> 3, s = c & 7;
        int4 d = *(const int4*)&L[row * 64 + ((s ^ (row & 7)) << 3)];
        *(int4*)(dst + c * 8) = d;           // lane-contiguous 1 KB per instr
    }
}

// ---------- dequant W_d v5: Btd[88][2048][64], LDS-staged (r17 control) ----------
__global__ __launch_bounds__(256) void dequant_wd5(
    const uint32_t* __restrict__ W, const float* __restrict__ S,
    __half* __restrict__ Bt)
{
    __shared__ __half L[256 * 64];   // 32 KB
    const int kt = blockIdx.y;                       // 0..87
    const int t  = threadIdx.x;
    const int n  = blockIdx.x * 256 + t;             // output col 0..2047
    uint32_t s2u = scale_s2u(S[(size_t)(kt >> 1) * HDIM + n]);
    #pragma unroll
    for (int j = 0; j < 8; ++j) {
        uint32_t w = W[(size_t)(kt * 8 + j) * HDIM + n];
        int4 d = dec8(w, s2u);
        *(int4*)&L[t * 64 + ((j ^ (t & 7)) << 3)] = d;
    }
    __syncthreads();
    __half* dst = Bt + (size_t)kt * G2_KSB + (size_t)blockIdx.x * 256 * 64;
    #pragma unroll
    for (int k = 0; k < 8; ++k) {
        int c = k * 256 + t;
        int row = c >> 3, s = c & 7;
        int4 d = *(const int4*)&L[row * 64 + ((s ^ (row & 7)) << 3)];
        *(int4*)(dst + c * 8) = d;
    }
}

// ---------- GEMM1 v19: faithful m201-style fine-interleave schedule.
// 256x256 tile, 8 waves (128x64), 4 phases/K-tile, 2 LDS buffers (128 KB),
// EXACTLY ONE half-tile (2 gl_lds) staged per phase, counted vmcnt(2) once
// per K-tile (never 0 mid-loop). Region-free analysis:
//   B(c) fully read after P2, A(c) after P3 ->
//   P1: B_h1(c+1)  P2: A_h0(c+1)  P3: A_h1(c+1)  P4: B_h0(c+2)
// Outstanding at P4 = 10 loads; vmcnt(2) leaves only B_h0(c+2) in flight. ----------
__global__ __launch_bounds__(512, 1) void gemm1_8x(
    const __half* __restrict__ A, const __half* __restrict__ Bt,
    __half* __restrict__ act)
{
    __shared__ __half Al[2][256 * 64];   // 2 x 32 KB
    __shared__ __half Bl[2][256 * 64];   // 2 x 32 KB  (128 KB)
    const int tid  = threadIdx.x;
    const int lane = tid & 63;
    const int wid  = tid >> 6;
    const int wm   = wid >> 2;   // 0..1 : A rows wm*128 (half wm)
    const int wn   = wid & 3;    // 0..3 : B rows wn*64 (half wn>>1)
    const int m0 = blockIdx.y * 256;
    const int n0 = blockIdx.x * 256;

    const __half* srcA[4];
    const __half* srcB[4];
    #pragma unroll
    for (int i = 0; i < 4; ++i) {
        int u = i * 512 + tid, row = u >> 3, s = u & 7, sl = s ^ (row & 7);
        srcA[i] = A  + (size_t)(m0 + row) * HDIM + sl * 8;
        srcB[i] = Bt + (size_t)(n0 + row) * 64 + sl * 8;
    }
    // half h (rows h*128..+128) = staging instrs 2h, 2h+1
    auto stA = [&](int buf, int kt, int h) {
        gl_lds16(srcA[2*h]   + (size_t)kt * 64, (char*)&Al[buf][0] + ((2*h)   * 512 + tid) * 16);
        gl_lds16(srcA[2*h+1] + (size_t)kt * 64, (char*)&Al[buf][0] + ((2*h+1) * 512 + tid) * 16);
    };
    auto stB = [&](int buf, int kt, int h) {
        gl_lds16(srcB[2*h]   + (size_t)kt * G1_KSB, (char*)&Bl[buf][0] + ((2*h)   * 512 + tid) * 16);
        gl_lds16(srcB[2*h+1] + (size_t)kt * G1_KSB, (char*)&Bl[buf][0] + ((2*h+1) * 512 + tid) * 16);
    };

    f32x4 acc[8][4];
    #pragma unroll
    for (int i = 0; i < 8; ++i)
        #pragma unroll
        for (int j = 0; j < 4; ++j) acc[i][j] = f32x4{0.f, 0.f, 0.f, 0.f};

    // hoisted LDS-read byte offsets
    int aoff[8][2], boff[4][2];
    #pragma unroll
    for (int mi = 0; mi < 8; ++mi)
        #pragma unroll
        for (int ks = 0; ks < 2; ++ks) {
            int kb = ks * 4 + (lane >> 4);
            int ra = wm * 128 + mi * 16 + (lane & 15);
            aoff[mi][ks] = ra * 128 + ((kb ^ (ra & 7)) << 4);
        }
    #pragma unroll
    for (int ni = 0; ni < 4; ++ni)
        #pragma unroll
        for (int ks = 0; ks < 2; ++ks) {
            int kb = ks * 4 + (lane >> 4);
            int rb = wn * 64 + ni * 16 + (lane & 15);
            boff[ni][ks] = rb * 128 + ((kb ^ (rb & 7)) << 4);
        }

    // prologue: K0 fully (8 loads) + B_h0(1) (2 loads); wait K0 (leave 2)
    stB(0, 0, 0); stB(0, 0, 1); stA(0, 0, 0); stA(0, 0, 1);
    stB(1, 1, 0);
    asm volatile("s_waitcnt vmcnt(2)" ::: "memory");
    asm volatile("s_barrier" ::: "memory");

    f16x8 a[4][2], b[4][2];
    for (int c = 0; c < 32; ++c) {
        const int buf = c & 1, nb = buf ^ 1;
        const char* Ac = (const char*)&Al[buf][0];
        const char* Bc = (const char*)&Bl[buf][0];
        const bool s1 = (c + 1) < 32;
        const bool s2 = (c + 2) < 32;

        // ---- P1: ds_read A mi0-3 (8) + B ni0-1 (4); stage B_h1(c+1); MFMA Q1 ----
        #pragma unroll
        for (int mi = 0; mi < 4; ++mi)
            #pragma unroll
            for (int kk = 0; kk < 2; ++kk)
                a[mi][kk] = *(const f16x8*)(Ac + aoff[mi][kk]);
        #pragma unroll
        for (int ni = 0; ni < 2; ++ni)
            #pragma unroll
            for (int kk = 0; kk < 2; ++kk)
                b[ni][kk] = *(const f16x8*)(Bc + boff[ni][kk]);
        if (s1) stB(nb, c + 1, 1);
        asm volatile("s_barrier" ::: "memory");
        asm volatile("s_waitcnt lgkmcnt(0)" ::: "memory");
        __builtin_amdgcn_s_setprio(1);
        #pragma unroll
        for (int mi = 0; mi < 4; ++mi)
            #pragma unroll
            for (int ni = 0; ni < 2; ++ni)
                #pragma unroll
                for (int kk = 0; kk < 2; ++kk)
                    acc[mi][ni] = __builtin_amdgcn_mfma_f32_16x16x32_f16(a[mi][kk], b[ni][kk], acc[mi][ni], 0, 0, 0);
        __builtin_amdgcn_s_setprio(0);
        asm volatile("s_barrier" ::: "memory");

        // ---- P2: ds_read B ni2-3 (4); stage A_h0(c+1); MFMA Q2 ----
        #pragma unroll
        for (int ni = 2; ni < 4; ++ni)
            #pragma unroll
            for (int kk = 0; kk < 2; ++kk)
                b[ni][kk] = *(const f16x8*)(Bc + boff[ni][kk]);
        if (s1) stA(nb, c + 1, 0);
        asm volatile("s_barrier" ::: "memory");
        asm volatile("s_waitcnt lgkmcnt(0)" ::: "memory");
        __builtin_amdgcn_s_setprio(1);
        #pragma unroll
        for (int mi = 0; mi < 4; ++mi)
            #pragma unroll
            for (int ni = 2; ni < 4; ++ni)
                #pragma unroll
                for (int kk = 0; kk < 2; ++kk)
                    acc[mi][ni] = __builtin_amdgcn_mfma_f32_16x16x32_f16(a[mi][kk], b[ni][kk], acc[mi][ni], 0, 0, 0);
        __builtin_amdgcn_s_setprio(0);
        asm volatile("s_barrier" ::: "memory");

        // ---- P3: ds_read A mi4-7 (8); stage A_h1(c+1); MFMA Q3 ----
        #pragma unroll
        for (int mi = 0; mi < 4; ++mi)
            #pragma unroll
            for (int kk = 0; kk < 2; ++kk)
                a[mi][kk] = *(const f16x8*)(Ac + aoff[mi + 4][kk]);
        if (s1) stA(nb, c + 1, 1);
        asm volatile("s_barrier" ::: "memory");
        asm volatile("s_waitcnt lgkmcnt(0)" ::: "memory");
        __builtin_amdgcn_s_setprio(1);
        #pragma unroll
        for (int mi = 0; mi < 4; ++mi)
            #pragma unroll
            for (int ni = 2; ni < 4; ++ni)
                #pragma unroll
                for (int kk = 0; kk < 2; ++kk)
                    acc[mi + 4][ni] = __builtin_amdgcn_mfma_f32_16x16x32_f16(a[mi][kk], b[ni][kk], acc[mi + 4][ni], 0, 0, 0);
        __builtin_amdgcn_s_setprio(0);
        asm volatile("s_barrier" ::: "memory");

        // ---- P4: stage B_h0(c+2); MFMA Q4 (A mi4-7 regs x B ni0-1 regs); vmcnt ----
        if (s2) stB(buf, c + 2, 0);
        __builtin_amdgcn_s_setprio(1);
        #pragma unroll
        for (int mi = 0; mi < 4; ++mi)
            #pragma unroll
            for (int ni = 0; ni < 2; ++ni)
                #pragma unroll
                for (int kk = 0; kk < 2; ++kk)
                    acc[mi + 4][ni] = __builtin_amdgcn_mfma_f32_16x16x32_f16(a[mi][kk], b[ni][kk], acc[mi + 4][ni], 0, 0, 0);
        __builtin_amdgcn_s_setprio(0);
        if (s2)      asm volatile("s_waitcnt vmcnt(2)" ::: "memory");
        else if (s1) asm volatile("s_waitcnt vmcnt(0)" ::: "memory");
        asm volatile("s_barrier" ::: "memory");
    }

    // epilogue: 32-col gate/up interleave -> ni=0,1 gate, ni=2,3 up; sigma slot
    const int pairbase = ((n0 + wn * 64) >> 6) * 32;
    #pragma unroll
    for (int mi = 0; mi < 8; ++mi) {
        #pragma unroll
        for (int q = 0; q < 2; ++q) {
            int gcol = pairbase + q * 16 + (lane & 15);
            int colstore = (gcol & ~7) | (((gcol & 3) << 1) | ((gcol >> 2) & 1));
            #pragma unroll
            for (int r = 0; r < 4; ++r) {
                int m = m0 + wm * 128 + mi * 16 + (lane >> 4) * 4 + r;
                float gv = acc[mi][q][r];
                float uv = acc[mi][q + 2][r];
                float sig = 1.0f / (1.0f + __expf(-gv));
                act[(size_t)m * IDIM + colstore] = __float2half(gv * sig * uv);
            }
        }
    }
}

// ---------- GEMM2 pre-dequant (r17 control) ----------
__global__ __launch_bounds__(256, 4) void gemm2_s(
    const __half* __restrict__ A, const __half* __restrict__ Bt,
    const float* __restrict__ moe, float* __restrict__ out)
{
    __shared__ __half Alds[BM * 64];   // 16 KB
    __shared__ __half Blds[BN * 64];   // 16 KB
    const int tid  = threadIdx.x;
    const int lane = tid & 63;
    const int wid  = tid >> 6;
    const int wm = wid >> 1, wn = wid & 1;
    const int m0 = blockIdx.y * BM;
    const int n0 = blockIdx.x * BN;

    f32x4 acc[4][4];
    #pragma unroll
    for (int i = 0; i < 4; ++i)
        #pragma unroll
        for (int j = 0; j < 4; ++j) acc[i][j] = f32x4{0.f, 0.f, 0.f, 0.f};

    const __half* srcA[4];
    const __half* srcB[4];
    #pragma unroll
    for (int i = 0; i < 4; ++i) {
        int u = i * 256 + tid, row = u >> 3, s = u & 7, sl = s ^ (row & 7);
        srcA[i] = A  + (size_t)(m0 + row) * IDIM + sl * 8;
        srcB[i] = Bt + (size_t)(n0 + row) * 64 + sl * 8;
    }

    int aoff[4][2], boff[4][2];
    #pragma unroll
    for (int f = 0; f < 4; ++f)
        #pragma unroll
        for (int ks = 0; ks < 2; ++ks) {
            int kb = ks * 4 + (lane >> 4);
            int ra = wm * 64 + f * 16 + (lane & 15);
            int rb = wn * 64 + f * 16 + (lane & 15);
            aoff[f][ks] = ra * 128 + ((kb ^ (ra & 7)) << 4);
            boff[f][ks] = rb * 128 + ((kb ^ (rb & 7)) << 4);
        }

    for (int kt = 0; kt < IDIM / 64; ++kt) {
        #pragma unroll
        for (int i = 0; i < 4; ++i) {
            int u = i * 256 + tid;
            gl_lds16(srcA[i], (char*)Alds + u * 16);
            gl_lds16(srcB[i], (char*)Blds + u * 16);
            srcA[i] += 64;
            srcB[i] += G2_KSB;
        }
        __syncthreads();
        #pragma unroll
        for (int ks = 0; ks < 2; ++ks) {
            f16x8 af[4], bf[4];
            #pragma unroll
            for (int f = 0; f < 4; ++f) {
                af[f] = *(const f16x8*)((const char*)Alds + aoff[f][ks]);
                bf[f] = *(const f16x8*)((const char*)Blds + boff[f][ks]);
            }
            #pragma unroll
            for (int mi = 0; mi < 4; ++mi)
                #pragma unroll
                for (int ni = 0; ni < 4; ++ni)
                    acc[mi][ni] = __builtin_amdgcn_mfma_f32_16x16x32_f16(af[mi], bf[ni], acc[mi][ni], 0, 0, 0);
        }
        __syncthreads();
    }
    #pragma unroll
    for (int mi = 0; mi < 4; ++mi) {
        #pragma unroll
        for (int ni = 0; ni < 4; ++ni) {
            int n = n0 + wn * 64 + ni * 16 + (lane & 15);
            #pragma unroll
            for (int r = 0; r < 4; ++r) {
                int m = m0 + wm * 64 + mi * 16 + (lane >> 4) * 4 + r;
                out[(size_t)m * HDIM + n] = moe[(size_t)m * HDIM + n] + acc[mi][ni][r];
            }
        }
    }
}

// ---------- GEMM1 standard 128^2 (fallback for gemm1 if 8x fails ws; also
// retained as the r17-measured kernel in case of quick revert) ----------
__global__ __launch_bounds__(256, 2) void gemm1_silu(
    const __half* __restrict__ A, const uint32_t* __restrict__ W,
    const float* __restrict__ S, __half* __restrict__ act)
{
    __shared__ __half Alds[BM * BK];
    __shared__ __half Blds[2][BN * BK];
    const int tid  = threadIdx.x;
    const int lane = tid & 63;
    const int wid  = tid >> 6;
    const int wm = wid >> 1, wn = wid & 1;
    const int m0 = blockIdx.y * BM;
    const int c0 = blockIdx.x * BN;

    f32x4 accg[4][4], accu[4][4];
    #pragma unroll
    for (int i = 0; i < 4; ++i)
        #pragma unroll
        for (int j = 0; j < 4; ++j) {
            accg[i][j] = f32x4{0.f, 0.f, 0.f, 0.f};
            accu[i][j] = f32x4{0.f, 0.f, 0.f, 0.f};
        }

    const int c = tid & 127;
    const int rbase = (tid >> 7) * 4;

    for (int kt = 0; kt < HDIM / BK; ++kt) {
        const int k0 = kt * BK;
        #pragma unroll
        for (int i = 0; i < 4; ++i) {
            int u = tid + i * 256;
            int row = u >> 3, kb = u & 7;
            int4 v = *(const int4*)(A + (size_t)(m0 + row) * HDIM + k0 + kb * 8);
            *(int4*)((char*)Alds + row * 128 + ((kb ^ (row & 7)) << 4)) = v;
        }
        const int g = k0 >> 7;
        #pragma unroll
        for (int p = 0; p < 2; ++p) {
            const int ncol = (p ? IDIM : 0) + c0 + c;
            uint32_t s2u = scale_s2u(S[(size_t)g * (2 * IDIM) + ncol]);
            #pragma unroll
            for (int i = 0; i < 4; ++i) {
                int rl = rbase + i;
                uint32_t w = W[(size_t)(kt * 8 + rl) * (2 * IDIM) + ncol];
                int4 d = dec8(w, s2u);
                *(int4*)((char*)&Blds[p][0] + c * 128 + ((rl ^ (c & 7)) << 4)) = d;
            }
        }
        __syncthreads();
        #pragma unroll
        for (int ks = 0; ks < 2; ++ks) {
            f16x8 af[4], bg[4], bu[4];
            const int kb = ks * 4 + (lane >> 4);
            #pragma unroll
            for (int mi = 0; mi < 4; ++mi) {
                int m = wm * 64 + mi * 16 + (lane & 15);
                af[mi] = *(const f16x8*)((const char*)Alds + m * 128 + ((kb ^ (m & 7)) << 4));
            }
            #pragma unroll
            for (int ni = 0; ni < 4; ++ni) {
                int n = wn * 64 + ni * 16 + (lane & 15);
                bg[ni] = *(const f16x8*)((const char*)&Blds[0][0] + n * 128 + ((kb ^ (n & 7)) << 4));
                bu[ni] = *(const f16x8*)((const char*)&Blds[1][0] + n * 128 + ((kb ^ (n & 7)) << 4));
            }
            #pragma unroll
            for (int mi = 0; mi < 4; ++mi)
                #pragma unroll
                for (int ni = 0; ni < 4; ++ni) {
                    accg[mi][ni] = __builtin_amdgcn_mfma_f32_16x16x32_f16(af[mi], bg[ni], accg[mi][ni], 0, 0, 0);
                    accu[mi][ni] = __builtin_amdgcn_mfma_f32_16x16x32_f16(af[mi], bu[ni], accu[mi][ni], 0, 0, 0);
                }
        }
        __syncthreads();
    }
    #pragma unroll
    for (int mi = 0; mi < 4; ++mi) {
        #pragma unroll
        for (int ni = 0; ni < 4; ++ni) {
            int nlog = c0 + wn * 64 + ni * 16 + (lane & 15);
            int ncol = (nlog & ~7) | (((nlog & 3) << 1) | ((nlog >> 2) & 1));
            #pragma unroll
            for (int r = 0; r < 4; ++r) {
                int m = m0 + wm * 64 + mi * 16 + (lane >> 4) * 4 + r;
                float gv = accg[mi][ni][r];
                float uv = accu[mi][ni][r];
                float sig = 1.0f / (1.0f + __expf(-gv));
                act[(size_t)m * IDIM + ncol] = __float2half(gv * sig * uv);
            }
        }
    }
}

// ---------- GEMM2 fused-decode fallback ----------
__global__ __launch_bounds__(256, 2) void gemm2_add(
    const __half* __restrict__ A, const uint32_t* __restrict__ W,
    const float* __restrict__ S, const float* __restrict__ moe,
    float* __restrict__ out)
{
    __shared__ __half Alds[BM * BK];
    __shared__ __half Blds[BN * BK];
    const int tid  = threadIdx.x;
    const int lane = tid & 63;
    const int wid  = tid >> 6;
    const int wm = wid >> 1, wn = wid & 1;
    const int m0 = blockIdx.y * BM;
    const int n0 = blockIdx.x * BN;

    f32x4 acc[4][4];
    #pragma unroll
    for (int i = 0; i < 4; ++i)
        #pragma unroll
        for (int j = 0; j < 4; ++j) acc[i][j] = f32x4{0.f, 0.f, 0.f, 0.f};

    const int c = tid & 127;
    const int rbase = (tid >> 7) * 4;

    for (int kt = 0; kt < IDIM / BK; ++kt) {
        const int k0 = kt * BK;
        #pragma unroll
        for (int i = 0; i < 4; ++i) {
            int u = tid + i * 256;
            int row = u >> 3, kb = u & 7;
            int4 v = *(const int4*)(A + (size_t)(m0 + row) * IDIM + k0 + kb * 8);
            *(int4*)((char*)Alds + row * 128 + ((kb ^ (row & 7)) << 4)) = v;
        }
        {
            const int g = k0 >> 7;
            const int ncol = n0 + c;
            uint32_t s2u = scale_s2u(S[(size_t)g * HDIM + ncol]);
            #pragma unroll
            for (int i = 0; i < 4; ++i) {
                int rl = rbase + i;
                uint32_t w = W[(size_t)(kt * 8 + rl) * HDIM + ncol];
                int4 d = dec8(w, s2u);
                *(int4*)((char*)Blds + c * 128 + ((rl ^ (c & 7)) << 4)) = d;
            }
        }
        __syncthreads();
        #pragma unroll
        for (int ks = 0; ks < 2; ++ks) {
            f16x8 af[4], bf[4];
            const int kb = ks * 4 + (lane >> 4);
            #pragma unroll
            for (int mi = 0; mi < 4; ++mi) {
                int m = wm * 64 + mi * 16 + (lane & 15);
                af[mi] = *(const f16x8*)((const char*)Alds + m * 128 + ((kb ^ (m & 7)) << 4));
            }
            #pragma unroll
            for (int ni = 0; ni < 4; ++ni) {
                int n = wn * 64 + ni * 16 + (lane & 15);
                bf[ni] = *(const f16x8*)((const char*)Blds + n * 128 + ((kb ^ (n & 7)) << 4));
            }
            #pragma unroll
            for (int mi = 0; mi < 4; ++mi)
                #pragma unroll
                for (int ni = 0; ni < 4; ++ni)
                    acc[mi][ni] = __builtin_amdgcn_mfma_f32_16x16x32_f16(af[mi], bf[ni], acc[mi][ni], 0, 0, 0);
        }
        __syncthreads();
    }
    #pragma unroll
    for (int mi = 0; mi < 4; ++mi) {
        #pragma unroll
        for (int ni = 0; ni < 4; ++ni) {
            int n = n0 + wn * 64 + ni * 16 + (lane & 15);
            #pragma unroll
            for (int r = 0; r < 4; ++r) {
                int m = m0 + wm * 64 + mi * 16 + (lane >> 4) * 4 + r;
                out[(size_t)m * HDIM + n] = moe[(size_t)m * HDIM + n] + acc[mi][ni][r];
            }
        }
    }
}

extern "C" void kernel_launch(void* const* d_in, const int* in_sizes, int n_in,
                              void* d_out, int out_size, void* d_ws, size_t ws_size,
                              hipStream_t stream) {
    const float*    hidden = (const float*)d_in[0];
    const float*    moe    = (const float*)d_in[1];
    const uint32_t* wgu    = (const uint32_t*)d_in[2];
    const float*    sgu    = (const float*)d_in[3];
    const uint32_t* wd     = (const uint32_t*)d_in[4];
    const float*    sd     = (const float*)d_in[5];
    float* out = (float*)d_out;

    const size_t sz_hidden = (size_t)TOKENS * HDIM * 2;      // 16.78 MB
    const size_t sz_act    = (size_t)TOKENS * IDIM * 2;      // 46.14 MB
    const size_t sz_wgu16  = (size_t)HDIM * 2 * IDIM * 2;    // 46.14 MB
    const size_t sz_wd16   = (size_t)IDIM * HDIM * 2;        // 23.07 MB

    __half* hidden_f16 = (__half*)d_ws;
    __half* act        = (__half*)((char*)d_ws + sz_hidden);
    __half* wgu16      = (__half*)((char*)d_ws + sz_hidden + sz_act);
    __half* wd16       = (__half*)((char*)d_ws + sz_hidden + sz_act + sz_wgu16);

    const size_t need_g1 = sz_hidden + sz_act + sz_wgu16;    // 109 MB
    const size_t need_g2 = need_g1 + sz_wd16;                // 132 MB (proven r6/r17)

    convert_hidden<<<dim3(TOKENS * HDIM / 8 / 256), dim3(256), 0, stream>>>(hidden, hidden_f16);

    if (ws_size >= need_g1) {
        dequant_wgu5<<<dim3(G1_NP / 256, 32), dim3(256), 0, stream>>>(wgu, sgu, wgu16);
        gemm1_8x<<<dim3(G1_NP / 256, TOKENS / 256), dim3(512), 0, stream>>>(hidden_f16, wgu16, act);
    } else {
        gemm1_silu<<<dim3(IDIM / BN, TOKENS / BM), dim3(256), 0, stream>>>(hidden_f16, wgu, sgu, act);
    }

    if (ws_size >= need_g2) {
        dequant_wd5<<<dim3(HDIM / 256, IDIM / 64), dim3(256), 0, stream>>>(wd, sd, wd16);
        gemm2_s<<<dim3(HDIM / BN, TOKENS / BM), dim3(256), 0, stream>>>(act, wd16, moe, out);
    } else {
        gemm2_add<<<dim3(HDIM / BN, TOKENS / BM), dim3(256), 0, stream>>>(act, wd, sd, moe, out);
    }
}

// Round 20
// 311.735 us; speedup vs baseline: 1.0403x; 1.0403x over previous
//
#include <hip/hip_runtime.h>
#include <hip/hip_fp16.h>
#include <stdint.h>

#define TOKENS 4096
#define HDIM   2048
#define IDIM   5632
#define BM 128
#define BN 128
#define BK 64

#define G1_NP  11264
#define G1_KSB (G1_NP * 64)    // halves per K-tile panel of Bt (gate/up)
#define G2_KSB (HDIM * 64)     // halves per K-tile panel of Btd (down)

typedef _Float16 f16x8 __attribute__((ext_vector_type(8)));
typedef float    f32x4 __attribute__((ext_vector_type(4)));

// ---------- fp4 decode helpers (verified rounds 1-19) ----------
__device__ __forceinline__ uint32_t dec2(uint32_t z, uint32_t s2u) {
    uint32_t sgn = (z << 12) & 0x80008000u;
    uint32_t h   = ((z << 9) & 0x0E000E00u) | sgn;
    __half2 hv = __builtin_bit_cast(__half2, h);
    __half2 sv = __builtin_bit_cast(__half2, s2u);
    __half2 r  = __hmul2(hv, sv);
    return __builtin_bit_cast(uint32_t, r);
}
__device__ __forceinline__ int4 dec8(uint32_t w, uint32_t s2u) {
    int4 d;
    d.x = (int)dec2( w        & 0x000F000Fu, s2u);
    d.y = (int)dec2((w >> 4)  & 0x000F000Fu, s2u);
    d.z = (int)dec2((w >> 8)  & 0x000F000Fu, s2u);
    d.w = (int)dec2((w >> 12) & 0x000F000Fu, s2u);
    return d;
}
__device__ __forceinline__ uint32_t scale_s2u(float sc) {
    uint16_t hs = __builtin_bit_cast(uint16_t, __float2half(sc * 16384.0f));
    return (uint32_t)hs * 0x00010001u;
}
__device__ __forceinline__ uint32_t packh(float lo, float hi) {
    __half2 h2 = __halves2half2(__float2half(lo), __float2half(hi));
    return __builtin_bit_cast(uint32_t, h2);
}
__device__ __forceinline__ void gl_lds16(const void* g, void* l) {
    __builtin_amdgcn_global_load_lds(
        (const __attribute__((address_space(1))) uint32_t*)g,
        (__attribute__((address_space(3))) uint32_t*)l, 16, 0, 0);
}

// ---------- hidden fp32 -> f16, sigma k-order within each 8-group ----------
__global__ __launch_bounds__(256) void convert_hidden(
    const float* __restrict__ src, __half* __restrict__ dst)
{
    int idx = blockIdx.x * 256 + threadIdx.x;   // one 8-group per thread
    const float4* s = (const float4*)src + (size_t)idx * 2;
    float4 a = s[0], b = s[1];                  // a = x0..x3, b = x4..x7
    int4 v;
    v.x = (int)packh(a.x, b.x);                 // pos 0,1 = x0,x4
    v.y = (int)packh(a.y, b.y);
    v.z = (int)packh(a.z, b.z);
    v.w = (int)packh(a.w, b.w);
    *((int4*)dst + idx) = v;
}

// ---------- dequant W_gu v5 (measured-best of 5 variants): 32-col gate/up
// interleave -> Bt[32][11264][64], linear k-word slots; LDS-staged so both
// read AND write instructions are wave-coalesced. ----------
__global__ __launch_bounds__(256) void dequant_wgu5(
    const uint32_t* __restrict__ W, const float* __restrict__ S,
    __half* __restrict__ Bt)
{
    __shared__ __half L[256 * 64];   // 32 KB
    const int kt = blockIdx.y;                       // 0..31
    const int t  = threadIdx.x;
    const int np = blockIdx.x * 256 + t;             // interleaved row
    const int sc = (np >> 6) * 32 + (np & 31) + (((np >> 5) & 1) ? IDIM : 0);
    uint32_t s2u = scale_s2u(S[(size_t)(kt >> 1) * (2 * IDIM) + sc]);
    #pragma unroll
    for (int j = 0; j < 8; ++j) {
        uint32_t w = W[(size_t)(kt * 8 + j) * (2 * IDIM) + sc];
        int4 d = dec8(w, s2u);
        *(int4*)&L[t * 64 + ((j ^ (t & 7)) << 3)] = d;   // bank-spread slot
    }
    __syncthreads();
    __half* dst = Bt + (size_t)kt * G1_KSB + (size_t)blockIdx.x * 256 * 64;
    #pragma unroll
    for (int k = 0; k < 8; ++k) {
        int c = k * 256 + t;                 // chunk: row=c>>3, word s=c&7
        int row = c >> 3, s = c & 7;
        int4 d = *(const int4*)&L[row * 64 + ((s ^ (row & 7)) << 3)];
        *(int4*)(dst + c * 8) = d;           // lane-contiguous 1 KB per instr
    }
}

// ---------- dequant W_d v5: Btd[88][2048][64], same LDS-staged structure ----------
__global__ __launch_bounds__(256) void dequant_wd5(
    const uint32_t* __restrict__ W, const float* __restrict__ S,
    __half* __restrict__ Bt)
{
    __shared__ __half L[256 * 64];   // 32 KB
    const int kt = blockIdx.y;                       // 0..87
    const int t  = threadIdx.x;
    const int n  = blockIdx.x * 256 + t;             // output col 0..2047
    uint32_t s2u = scale_s2u(S[(size_t)(kt >> 1) * HDIM + n]);
    #pragma unroll
    for (int j = 0; j < 8; ++j) {
        uint32_t w = W[(size_t)(kt * 8 + j) * HDIM + n];
        int4 d = dec8(w, s2u);
        *(int4*)&L[t * 64 + ((j ^ (t & 7)) << 3)] = d;
    }
    __syncthreads();
    __half* dst = Bt + (size_t)kt * G2_KSB + (size_t)blockIdx.x * 256 * 64;
    #pragma unroll
    for (int k = 0; k < 8; ++k) {
        int c = k * 256 + t;
        int row = c >> 3, s = c & 7;
        int4 d = *(const int4*)&L[row * 64 + ((s ^ (row & 7)) << 3)];
        *(int4*)(dst + c * 8) = d;
    }
}

// ---------- GEMM1: session-best kernel (176 us, 53% MfmaUtil, 0 conflicts).
// 128x128 tile, 256 thr, 4 waves (64x64), single-buffer 32 KB LDS, gl_lds
// staging with per-lane source swizzle, hoisted LDS-read offsets.
// Epilogue: 32-col gate/up interleave (ni=0,1 gate / ni=2,3 up). ----------
__global__ __launch_bounds__(256, 4) void gemm1_s(
    const __half* __restrict__ A, const __half* __restrict__ Bt,
    __half* __restrict__ act)
{
    __shared__ __half Alds[BM * 64];   // 16 KB
    __shared__ __half Blds[BN * 64];   // 16 KB
    const int tid  = threadIdx.x;
    const int lane = tid & 63;
    const int wid  = tid >> 6;
    const int wm = wid >> 1, wn = wid & 1;
    const int m0 = blockIdx.y * BM;
    const int n0 = blockIdx.x * BN;

    f32x4 acc[4][4];
    #pragma unroll
    for (int i = 0; i < 4; ++i)
        #pragma unroll
        for (int j = 0; j < 4; ++j) acc[i][j] = f32x4{0.f, 0.f, 0.f, 0.f};

    const __half* srcA[4];
    const __half* srcB[4];
    #pragma unroll
    for (int i = 0; i < 4; ++i) {
        int u = i * 256 + tid, row = u >> 3, s = u & 7, sl = s ^ (row & 7);
        srcA[i] = A  + (size_t)(m0 + row) * HDIM + sl * 8;
        srcB[i] = Bt + (size_t)(n0 + row) * 64 + sl * 8;
    }

    int aoff[4][2], boff[4][2];
    #pragma unroll
    for (int f = 0; f < 4; ++f)
        #pragma unroll
        for (int ks = 0; ks < 2; ++ks) {
            int kb = ks * 4 + (lane >> 4);
            int ra = wm * 64 + f * 16 + (lane & 15);
            int rb = wn * 64 + f * 16 + (lane & 15);
            aoff[f][ks] = ra * 128 + ((kb ^ (ra & 7)) << 4);
            boff[f][ks] = rb * 128 + ((kb ^ (rb & 7)) << 4);
        }

    for (int kt = 0; kt < HDIM / 64; ++kt) {
        #pragma unroll
        for (int i = 0; i < 4; ++i) {
            int u = i * 256 + tid;
            gl_lds16(srcA[i], (char*)Alds + u * 16);
            gl_lds16(srcB[i], (char*)Blds + u * 16);
            srcA[i] += 64;
            srcB[i] += G1_KSB;
        }
        __syncthreads();
        #pragma unroll
        for (int ks = 0; ks < 2; ++ks) {
            f16x8 af[4], bf[4];
            #pragma unroll
            for (int f = 0; f < 4; ++f) {
                af[f] = *(const f16x8*)((const char*)Alds + aoff[f][ks]);
                bf[f] = *(const f16x8*)((const char*)Blds + boff[f][ks]);
            }
            #pragma unroll
            for (int mi = 0; mi < 4; ++mi)
                #pragma unroll
                for (int ni = 0; ni < 4; ++ni)
                    acc[mi][ni] = __builtin_amdgcn_mfma_f32_16x16x32_f16(af[mi], bf[ni], acc[mi][ni], 0, 0, 0);
        }
        __syncthreads();
    }

    // epilogue: 32-col interleave -> ni=0,1 gate cols, ni=2,3 up cols. sigma slot.
    const int pairbase = ((n0 + wn * 64) >> 6) * 32;
    #pragma unroll
    for (int mi = 0; mi < 4; ++mi) {
        #pragma unroll
        for (int q = 0; q < 2; ++q) {
            int gcol = pairbase + q * 16 + (lane & 15);
            int colstore = (gcol & ~7) | (((gcol & 3) << 1) | ((gcol >> 2) & 1));
            #pragma unroll
            for (int r = 0; r < 4; ++r) {
                int m = m0 + wm * 64 + mi * 16 + (lane >> 4) * 4 + r;
                float gv = acc[mi][q][r];
                float uv = acc[mi][q + 2][r];
                float sig = 1.0f / (1.0f + __expf(-gv));
                act[(size_t)m * IDIM + colstore] = __float2half(gv * sig * uv);
            }
        }
    }
}

// ---------- GEMM2 pre-dequant (r17, ~72 us): gemm1_s twin, zero in-loop
// decode, moe-add epilogue ----------
__global__ __launch_bounds__(256, 4) void gemm2_s(
    const __half* __restrict__ A, const __half* __restrict__ Bt,
    const float* __restrict__ moe, float* __restrict__ out)
{
    __shared__ __half Alds[BM * 64];   // 16 KB
    __shared__ __half Blds[BN * 64];   // 16 KB
    const int tid  = threadIdx.x;
    const int lane = tid & 63;
    const int wid  = tid >> 6;
    const int wm = wid >> 1, wn = wid & 1;
    const int m0 = blockIdx.y * BM;
    const int n0 = blockIdx.x * BN;

    f32x4 acc[4][4];
    #pragma unroll
    for (int i = 0; i < 4; ++i)
        #pragma unroll
        for (int j = 0; j < 4; ++j) acc[i][j] = f32x4{0.f, 0.f, 0.f, 0.f};

    const __half* srcA[4];
    const __half* srcB[4];
    #pragma unroll
    for (int i = 0; i < 4; ++i) {
        int u = i * 256 + tid, row = u >> 3, s = u & 7, sl = s ^ (row & 7);
        srcA[i] = A  + (size_t)(m0 + row) * IDIM + sl * 8;
        srcB[i] = Bt + (size_t)(n0 + row) * 64 + sl * 8;
    }

    int aoff[4][2], boff[4][2];
    #pragma unroll
    for (int f = 0; f < 4; ++f)
        #pragma unroll
        for (int ks = 0; ks < 2; ++ks) {
            int kb = ks * 4 + (lane >> 4);
            int ra = wm * 64 + f * 16 + (lane & 15);
            int rb = wn * 64 + f * 16 + (lane & 15);
            aoff[f][ks] = ra * 128 + ((kb ^ (ra & 7)) << 4);
            boff[f][ks] = rb * 128 + ((kb ^ (rb & 7)) << 4);
        }

    for (int kt = 0; kt < IDIM / 64; ++kt) {
        #pragma unroll
        for (int i = 0; i < 4; ++i) {
            int u = i * 256 + tid;
            gl_lds16(srcA[i], (char*)Alds + u * 16);
            gl_lds16(srcB[i], (char*)Blds + u * 16);
            srcA[i] += 64;
            srcB[i] += G2_KSB;
        }
        __syncthreads();
        #pragma unroll
        for (int ks = 0; ks < 2; ++ks) {
            f16x8 af[4], bf[4];
            #pragma unroll
            for (int f = 0; f < 4; ++f) {
                af[f] = *(const f16x8*)((const char*)Alds + aoff[f][ks]);
                bf[f] = *(const f16x8*)((const char*)Blds + boff[f][ks]);
            }
            #pragma unroll
            for (int mi = 0; mi < 4; ++mi)
                #pragma unroll
                for (int ni = 0; ni < 4; ++ni)
                    acc[mi][ni] = __builtin_amdgcn_mfma_f32_16x16x32_f16(af[mi], bf[ni], acc[mi][ni], 0, 0, 0);
        }
        __syncthreads();
    }
    #pragma unroll
    for (int mi = 0; mi < 4; ++mi) {
        #pragma unroll
        for (int ni = 0; ni < 4; ++ni) {
            int n = n0 + wn * 64 + ni * 16 + (lane & 15);
            #pragma unroll
            for (int r = 0; r < 4; ++r) {
                int m = m0 + wm * 64 + mi * 16 + (lane >> 4) * 4 + r;
                out[(size_t)m * HDIM + n] = moe[(size_t)m * HDIM + n] + acc[mi][ni][r];
            }
        }
    }
}

// ---------- round-1 fused-decode GEMM1 (fallback if ws too small) ----------
__global__ __launch_bounds__(256, 2) void gemm1_silu(
    const __half* __restrict__ A, const uint32_t* __restrict__ W,
    const float* __restrict__ S, __half* __restrict__ act)
{
    __shared__ __half Alds[BM * BK];
    __shared__ __half Blds[2][BN * BK];
    const int tid  = threadIdx.x;
    const int lane = tid & 63;
    const int wid  = tid >> 6;
    const int wm = wid >> 1, wn = wid & 1;
    const int m0 = blockIdx.y * BM;
    const int c0 = blockIdx.x * BN;

    f32x4 accg[4][4], accu[4][4];
    #pragma unroll
    for (int i = 0; i < 4; ++i)
        #pragma unroll
        for (int j = 0; j < 4; ++j) {
            accg[i][j] = f32x4{0.f, 0.f, 0.f, 0.f};
            accu[i][j] = f32x4{0.f, 0.f, 0.f, 0.f};
        }

    const int c = tid & 127;
    const int rbase = (tid >> 7) * 4;

    for (int kt = 0; kt < HDIM / BK; ++kt) {
        const int k0 = kt * BK;
        #pragma unroll
        for (int i = 0; i < 4; ++i) {
            int u = tid + i * 256;
            int row = u >> 3, kb = u & 7;
            int4 v = *(const int4*)(A + (size_t)(m0 + row) * HDIM + k0 + kb * 8);
            *(int4*)((char*)Alds + row * 128 + ((kb ^ (row & 7)) << 4)) = v;
        }
        const int g = k0 >> 7;
        #pragma unroll
        for (int p = 0; p < 2; ++p) {
            const int ncol = (p ? IDIM : 0) + c0 + c;
            uint32_t s2u = scale_s2u(S[(size_t)g * (2 * IDIM) + ncol]);
            #pragma unroll
            for (int i = 0; i < 4; ++i) {
                int rl = rbase + i;
                uint32_t w = W[(size_t)(kt * 8 + rl) * (2 * IDIM) + ncol];
                int4 d = dec8(w, s2u);
                *(int4*)((char*)&Blds[p][0] + c * 128 + ((rl ^ (c & 7)) << 4)) = d;
            }
        }
        __syncthreads();
        #pragma unroll
        for (int ks = 0; ks < 2; ++ks) {
            f16x8 af[4], bg[4], bu[4];
            const int kb = ks * 4 + (lane >> 4);
            #pragma unroll
            for (int mi = 0; mi < 4; ++mi) {
                int m = wm * 64 + mi * 16 + (lane & 15);
                af[mi] = *(const f16x8*)((const char*)Alds + m * 128 + ((kb ^ (m & 7)) << 4));
            }
            #pragma unroll
            for (int ni = 0; ni < 4; ++ni) {
                int n = wn * 64 + ni * 16 + (lane & 15);
                bg[ni] = *(const f16x8*)((const char*)&Blds[0][0] + n * 128 + ((kb ^ (n & 7)) << 4));
                bu[ni] = *(const f16x8*)((const char*)&Blds[1][0] + n * 128 + ((kb ^ (n & 7)) << 4));
            }
            #pragma unroll
            for (int mi = 0; mi < 4; ++mi)
                #pragma unroll
                for (int ni = 0; ni < 4; ++ni) {
                    accg[mi][ni] = __builtin_amdgcn_mfma_f32_16x16x32_f16(af[mi], bg[ni], accg[mi][ni], 0, 0, 0);
                    accu[mi][ni] = __builtin_amdgcn_mfma_f32_16x16x32_f16(af[mi], bu[ni], accu[mi][ni], 0, 0, 0);
                }
        }
        __syncthreads();
    }
    #pragma unroll
    for (int mi = 0; mi < 4; ++mi) {
        #pragma unroll
        for (int ni = 0; ni < 4; ++ni) {
            int nlog = c0 + wn * 64 + ni * 16 + (lane & 15);
            int ncol = (nlog & ~7) | (((nlog & 3) << 1) | ((nlog >> 2) & 1));
            #pragma unroll
            for (int r = 0; r < 4; ++r) {
                int m = m0 + wm * 64 + mi * 16 + (lane >> 4) * 4 + r;
                float gv = accg[mi][ni][r];
                float uv = accu[mi][ni][r];
                float sig = 1.0f / (1.0f + __expf(-gv));
                act[(size_t)m * IDIM + ncol] = __float2half(gv * sig * uv);
            }
        }
    }
}

// ---------- GEMM2 fused-decode fallback ----------
__global__ __launch_bounds__(256, 2) void gemm2_add(
    const __half* __restrict__ A, const uint32_t* __restrict__ W,
    const float* __restrict__ S, const float* __restrict__ moe,
    float* __restrict__ out)
{
    __shared__ __half Alds[BM * BK];
    __shared__ __half Blds[BN * BK];
    const int tid  = threadIdx.x;
    const int lane = tid & 63;
    const int wid  = tid >> 6;
    const int wm = wid >> 1, wn = wid & 1;
    const int m0 = blockIdx.y * BM;
    const int n0 = blockIdx.x * BN;

    f32x4 acc[4][4];
    #pragma unroll
    for (int i = 0; i < 4; ++i)
        #pragma unroll
        for (int j = 0; j < 4; ++j) acc[i][j] = f32x4{0.f, 0.f, 0.f, 0.f};

    const int c = tid & 127;
    const int rbase = (tid >> 7) * 4;

    for (int kt = 0; kt < IDIM / BK; ++kt) {
        const int k0 = kt * BK;
        #pragma unroll
        for (int i = 0; i < 4; ++i) {
            int u = tid + i * 256;
            int row = u >> 3, kb = u & 7;
            int4 v = *(const int4*)(A + (size_t)(m0 + row) * IDIM + k0 + kb * 8);
            *(int4*)((char*)Alds + row * 128 + ((kb ^ (row & 7)) << 4)) = v;
        }
        {
            const int g = k0 >> 7;
            const int ncol = n0 + c;
            uint32_t s2u = scale_s2u(S[(size_t)g * HDIM + ncol]);
            #pragma unroll
            for (int i = 0; i < 4; ++i) {
                int rl = rbase + i;
                uint32_t w = W[(size_t)(kt * 8 + rl) * HDIM + ncol];
                int4 d = dec8(w, s2u);
                *(int4*)((char*)Blds + c * 128 + ((rl ^ (c & 7)) << 4)) = d;
            }
        }
        __syncthreads();
        #pragma unroll
        for (int ks = 0; ks < 2; ++ks) {
            f16x8 af[4], bf[4];
            const int kb = ks * 4 + (lane >> 4);
            #pragma unroll
            for (int mi = 0; mi < 4; ++mi) {
                int m = wm * 64 + mi * 16 + (lane & 15);
                af[mi] = *(const f16x8*)((const char*)Alds + m * 128 + ((kb ^ (m & 7)) << 4));
            }
            #pragma unroll
            for (int ni = 0; ni < 4; ++ni) {
                int n = wn * 64 + ni * 16 + (lane & 15);
                bf[ni] = *(const f16x8*)((const char*)Blds + n * 128 + ((kb ^ (n & 7)) << 4));
            }
            #pragma unroll
            for (int mi = 0; mi < 4; ++mi)
                #pragma unroll
                for (int ni = 0; ni < 4; ++ni)
                    acc[mi][ni] = __builtin_amdgcn_mfma_f32_16x16x32_f16(af[mi], bf[ni], acc[mi][ni], 0, 0, 0);
        }
        __syncthreads();
    }
    #pragma unroll
    for (int mi = 0; mi < 4; ++mi) {
        #pragma unroll
        for (int ni = 0; ni < 4; ++ni) {
            int n = n0 + wn * 64 + ni * 16 + (lane & 15);
            #pragma unroll
            for (int r = 0; r < 4; ++r) {
                int m = m0 + wm * 64 + mi * 16 + (lane >> 4) * 4 + r;
                out[(size_t)m * HDIM + n] = moe[(size_t)m * HDIM + n] + acc[mi][ni][r];
            }
        }
    }
}

extern "C" void kernel_launch(void* const* d_in, const int* in_sizes, int n_in,
                              void* d_out, int out_size, void* d_ws, size_t ws_size,
                              hipStream_t stream) {
    const float*    hidden = (const float*)d_in[0];
    const float*    moe    = (const float*)d_in[1];
    const uint32_t* wgu    = (const uint32_t*)d_in[2];
    const float*    sgu    = (const float*)d_in[3];
    const uint32_t* wd     = (const uint32_t*)d_in[4];
    const float*    sd     = (const float*)d_in[5];
    float* out = (float*)d_out;

    const size_t sz_hidden = (size_t)TOKENS * HDIM * 2;      // 16.78 MB
    const size_t sz_act    = (size_t)TOKENS * IDIM * 2;      // 46.14 MB
    const size_t sz_wgu16  = (size_t)HDIM * 2 * IDIM * 2;    // 46.14 MB
    const size_t sz_wd16   = (size_t)IDIM * HDIM * 2;        // 23.07 MB

    __half* hidden_f16 = (__half*)d_ws;
    __half* act        = (__half*)((char*)d_ws + sz_hidden);
    __half* wgu16      = (__half*)((char*)d_ws + sz_hidden + sz_act);
    __half* wd16       = (__half*)((char*)d_ws + sz_hidden + sz_act + sz_wgu16);

    const size_t need_g1 = sz_hidden + sz_act + sz_wgu16;    // 109 MB
    const size_t need_g2 = need_g1 + sz_wd16;                // 132 MB (proven r6/r17)

    convert_hidden<<<dim3(TOKENS * HDIM / 8 / 256), dim3(256), 0, stream>>>(hidden, hidden_f16);

    if (ws_size >= need_g1) {
        dequant_wgu5<<<dim3(G1_NP / 256, 32), dim3(256), 0, stream>>>(wgu, sgu, wgu16);
        gemm1_s<<<dim3(G1_NP / BN, TOKENS / BM), dim3(256), 0, stream>>>(hidden_f16, wgu16, act);
    } else {
        gemm1_silu<<<dim3(IDIM / BN, TOKENS / BM), dim3(256), 0, stream>>>(hidden_f16, wgu, sgu, act);
    }

    if (ws_size >= need_g2) {
        dequant_wd5<<<dim3(HDIM / 256, IDIM / 64), dim3(256), 0, stream>>>(wd, sd, wd16);
        gemm2_s<<<dim3(HDIM / BN, TOKENS / BM), dim3(256), 0, stream>>>(act, wd16, moe, out);
    } else {
        gemm2_add<<<dim3(HDIM / BN, TOKENS / BM), dim3(256), 0, stream>>>(act, wd, sd, moe, out);
    }
}